// Round 6
// baseline (4344.096 us; speedup 1.0000x reference)
//
#include <hip/hip_runtime.h>
#include <math.h>

// Problem dims
#define S_LEN  512
#define BATCH  64
#define E_DIM  512
#define H_DIM  512
#define G4     2048          // 4*H
#define VOCAB  32000
#define NWORK  16            // persistent LSTM worker slots
#define GRID_LSTM 256        // overdispatch; workers self-select onto ONE XCD

// s_memrealtime ticks (~100 MHz) — used ONLY in one-time team formation
#define RT_1MS   100000ull
#define RT_200US 20000ull

typedef int v4i __attribute__((ext_vector_type(4)));
typedef unsigned long long u64;

// Workspace layout (bytes). Total ~19.0 MiB.  (R2 layout.)
// O_BAR team area (memset-zeroed each launch):
//   team[0]=leader flag (xcd+1), team[1]=claim ctr, team[3]=xcd census bitmask,
//   team[4]=entry ctr, team[8..23]=per-slot (xcd+1), 0=empty
// h exchange: 2 slots x 64 batches x 64 units x 16B ({8 codes, 4B tag, 4B pad})
#define O_BAR   0
#define O_MAX   256                       // 4 uints: maxabs emb, ih, hh, fc
#define O_H8    512                       // 2 * 65536 B tagged h units
#define O_FC8   131584                    // 1024 int8
#define O_WIH8  132608                    // 2048*512 int8 (1 MiB)
#define O_WHH8  (O_WIH8 + 1048576)
#define O_X8    (O_WHH8 + 1048576)        // 512*64*512 int8 (16 MiB), t-major

__device__ __forceinline__ float clampf(float x, float lo, float hi) {
    return fminf(fmaxf(x, lo), hi);
}

// k = ceil(log2(maxabs/127)) via frexp (exact, no transcendental)
__device__ __forceinline__ int scale_exp(float maxabs) {
    double t = (double)maxabs / 127.0;
    int e; double f = frexp(t, &e);
    return (f == 0.5) ? (e - 1) : e;
}

// ---- XLA-CPU / Eigen fast tanh (f32), bit-exact vs the jax-CPU golden ------
__device__ __forceinline__ float xla_tanhf(float x) {
    if (fabsf(x) < 0.0004f) return x;
    float xc = fminf(fmaxf(x, -7.90531110763549805f), 7.90531110763549805f);
    float x2 = __fmul_rn(xc, xc);
    float p = fmaf(x2, -2.76076847742355e-16f, 2.00018790482477e-13f);
    p = fmaf(x2, p, -8.60467152213735e-11f);
    p = fmaf(x2, p, 5.12229709037114e-08f);
    p = fmaf(x2, p, 1.48572235717979e-05f);
    p = fmaf(x2, p, 6.37261928875436e-04f);
    p = fmaf(x2, p, 4.89352455891786e-03f);
    p = __fmul_rn(xc, p);
    float q = fmaf(x2, 1.19825839466702e-06f, 1.18534705686654e-04f);
    q = fmaf(x2, q, 2.26843463243900e-03f);
    q = fmaf(x2, q, 4.89352518554385e-03f);
    return __fdiv_rn(p, q);
}

// ---------------- maxabs reduction ----------------
__global__ void k_maxabs(const float* __restrict__ x, int n, unsigned* __restrict__ out) {
    unsigned m = 0;
    for (int i = blockIdx.x * blockDim.x + threadIdx.x; i < n; i += gridDim.x * blockDim.x)
        m = max(m, __float_as_uint(fabsf(x[i])));
    #pragma unroll
    for (int o = 32; o > 0; o >>= 1) {
        unsigned other = (unsigned)__shfl_down((int)m, o, 64);
        m = max(m, other);
    }
    __shared__ unsigned sm[4];
    if ((threadIdx.x & 63) == 0) sm[threadIdx.x >> 6] = m;
    __syncthreads();
    if (threadIdx.x == 0) {
        unsigned r = sm[0];
        for (int w = 1; w < (int)(blockDim.x >> 6); w++) r = max(r, sm[w]);
        atomicMax(out, r);
    }
}

// ---------------- weight quantization (exact: pow2 scale) ----------------
__global__ void k_quantw(const float* __restrict__ w, int n, const unsigned* __restrict__ mx,
                         signed char* __restrict__ q) {
    float inv = ldexpf(1.0f, -scale_exp(__uint_as_float(*mx)));
    for (int i = blockIdx.x * blockDim.x + threadIdx.x; i < n; i += gridDim.x * blockDim.x) {
        float v = clampf(rintf(w[i] * inv), -128.0f, 127.0f);
        q[i] = (signed char)(int)v;
    }
}

// ---------------- embedding lookup + double quantization (exact: pow2 scales) ----
__global__ void k_embed(const float* __restrict__ emb, const int* __restrict__ text,
                        const unsigned* __restrict__ mx, signed char* __restrict__ x8) {
    int row = blockIdx.x;                       // b*S + s (text is [B,S] row-major)
    int b = row >> 9, s = row & 511;
    int tok = text[row];
    int ke = scale_exp(__uint_as_float(*mx));
    float inv = ldexpf(1.0f, -ke);
    float sc2 = ldexpf(1.0f, ke + 4);
    const float4* src = (const float4*)(emb + (size_t)tok * E_DIM);
    char4* dst = (char4*)(x8 + (size_t)(s * BATCH + b) * E_DIM);
    float4 v = src[threadIdx.x];
    char4 c;
    float q;
    q = clampf(rintf(v.x * inv), -128.f, 127.f); c.x = (signed char)(int)clampf(rintf(q * sc2), -128.f, 127.f);
    q = clampf(rintf(v.y * inv), -128.f, 127.f); c.y = (signed char)(int)clampf(rintf(q * sc2), -128.f, 127.f);
    q = clampf(rintf(v.z * inv), -128.f, 127.f); c.z = (signed char)(int)clampf(rintf(q * sc2), -128.f, 127.f);
    q = clampf(rintf(v.w * inv), -128.f, 127.f); c.w = (signed char)(int)clampf(rintf(q * sc2), -128.f, 127.f);
    dst[threadIdx.x] = c;
}

#define MKFRAG(a, b) ((v4i){(a)[0], (a)[1], (b)[0], (b)[1]})

// Poll + load h[t] fragments. FLAGS selects coherence scope (gfx940+ {sc1,sc0}):
//   "sc0"     — XCD scope: serviced by the shared per-XCD L2 (~300cy). Valid
//               ONLY for the verified single-XCD team (R2: correct, absmax 0).
//   "sc0 sc1" — system scope: the proven baseline path.
#define H_POLL(FLAGS)                                                        \
    asm volatile(                                                            \
        "global_load_dwordx4 %0,  %16, off " FLAGS "\n\t"                    \
        "global_load_dwordx4 %1,  %16, off offset:16 " FLAGS "\n\t"          \
        "global_load_dwordx4 %2,  %16, off offset:128 " FLAGS "\n\t"         \
        "global_load_dwordx4 %3,  %16, off offset:144 " FLAGS "\n\t"         \
        "global_load_dwordx4 %4,  %16, off offset:256 " FLAGS "\n\t"         \
        "global_load_dwordx4 %5,  %16, off offset:272 " FLAGS "\n\t"         \
        "global_load_dwordx4 %6,  %16, off offset:384 " FLAGS "\n\t"         \
        "global_load_dwordx4 %7,  %16, off offset:400 " FLAGS "\n\t"         \
        "global_load_dwordx4 %8,  %16, off offset:512 " FLAGS "\n\t"         \
        "global_load_dwordx4 %9,  %16, off offset:528 " FLAGS "\n\t"         \
        "global_load_dwordx4 %10, %16, off offset:640 " FLAGS "\n\t"         \
        "global_load_dwordx4 %11, %16, off offset:656 " FLAGS "\n\t"         \
        "global_load_dwordx4 %12, %16, off offset:768 " FLAGS "\n\t"         \
        "global_load_dwordx4 %13, %16, off offset:784 " FLAGS "\n\t"         \
        "global_load_dwordx4 %14, %16, off offset:896 " FLAGS "\n\t"         \
        "global_load_dwordx4 %15, %16, off offset:912 " FLAGS "\n\t"         \
        "s_waitcnt vmcnt(0)"                                                 \
        : "=&v"(u0), "=&v"(u1), "=&v"(u2), "=&v"(u3),                        \
          "=&v"(u4), "=&v"(u5), "=&v"(u6), "=&v"(u7),                        \
          "=&v"(u8), "=&v"(u9), "=&v"(u10), "=&v"(u11),                      \
          "=&v"(u12), "=&v"(u13), "=&v"(u14), "=&v"(u15)                     \
        : "v"(ha)                                                            \
        : "memory")

#define H_TAGOK ((u0[2] == tg) & (u1[2] == tg) & (u2[2] == tg) & (u3[2] == tg)    \
               & (u4[2] == tg) & (u5[2] == tg) & (u6[2] == tg) & (u7[2] == tg)    \
               & (u8[2] == tg) & (u9[2] == tg) & (u10[2] == tg) & (u11[2] == tg)  \
               & (u12[2] == tg) & (u13[2] == tg) & (u14[2] == tg) & (u15[2] == tg))

// watchdog fallback: republish this wave's own slot lines system-visible,
// switch to the proven sc0 sc1 mode. Closed-loop coupling ensures every wave
// eventually does this if anyone does ->团队-wide fallback terminates.
#define FALLBACK_SLOW                                                        \
    do {                                                                     \
        fast = false;                                                        \
        _Pragma("unroll")                                                    \
        for (int sl = 0; sl < 2; sl++) {                                     \
            u64 pa_ = paddr_base + (u64)sl * 65536;                          \
            v4i val_;                                                        \
            asm volatile("global_load_dwordx4 %0, %1, off sc0\n\t"           \
                         "s_waitcnt vmcnt(0)"                                \
                         : "=&v"(val_) : "v"(pa_) : "memory");               \
            asm volatile("global_store_dwordx4 %0, %1, off sc0 sc1"          \
                         :: "v"(pa_), "v"(val_) : "memory");                 \
        }                                                                    \
    } while (0)

// ---------------- persistent fused LSTM, barrier-free tagged dataflow ----------
// R5 post-mortem: at system scope the wait is genuine visibility latency (a
// 7x poll-traffic cut changed nothing) -> the only big lever is physical
// locality: the single-XCD team (R2: formation + sc0 protocol CORRECT).
// R2's 3x slowdown is attributed to two loop defects, both removed here:
//   1. s_memrealtime every poll round (SMEM op + lgkm wait, serializing a
//      ~300cy L2 loop) -> watchdogs are now PURE ITERATION COUNTERS.
//   2. 16x dwordx4 per wave per round at L2 rate (~13 req/cy vs ~16-channel
//      L2) -> discovery is now a 16-lane 1-dword probe (one tag per
//      producer-wave publish-store; lanes 16-63 duplicate & merge), paced by
//      s_sleep(2); the verified 16-load tagged round then runs ~once/step.
// Slow fallback = exact baseline (no probe — R5 lesson). Numerics frozen.
__global__ __launch_bounds__(256, 1) void k_lstm(
    const signed char* __restrict__ wih8, const signed char* __restrict__ whh8,
    const signed char* __restrict__ x8, const float* __restrict__ b_ih,
    const float* __restrict__ b_hh, const unsigned* __restrict__ mx,
    signed char* __restrict__ h8, unsigned* __restrict__ team) {
    __shared__ __attribute__((aligned(16))) signed char wih_lds[128 * 528]; // rows padded 512->528
    __shared__ __attribute__((aligned(16))) signed char hstage[BATCH * 32]; // [b][jloc] codes
    __shared__ float lut_sig[256];
    __shared__ float lut_tnh[256];
    __shared__ int s_g, s_homog;

    // ---- team formation (thread 0 of each WG; one-time, memrealtime-bounded) ----
    if (threadIdx.x == 0) {
        unsigned xcd = __builtin_amdgcn_s_getreg(6164) & 0xfu;   // HW_REG_XCC_ID[3:0]
        __hip_atomic_fetch_or(&team[3], 1u << xcd, __ATOMIC_RELAXED, __HIP_MEMORY_SCOPE_AGENT);
        __hip_atomic_fetch_add(&team[4], 1u, __ATOMIC_RELAXED, __HIP_MEMORY_SCOPE_AGENT);
        int g = -1;
        u64 t0 = __builtin_amdgcn_s_memrealtime();
        if (blockIdx.x == 0) {
            g = 0;
            __hip_atomic_store(&team[8], xcd + 1u, __ATOMIC_RELEASE, __HIP_MEMORY_SCOPE_AGENT);
            __hip_atomic_store(&team[0], xcd + 1u, __ATOMIC_RELEASE, __HIP_MEMORY_SCOPE_AGENT);
        } else {
            unsigned f;
            for (;;) {
                f = __hip_atomic_load(&team[0], __ATOMIC_ACQUIRE, __HIP_MEMORY_SCOPE_AGENT);
                if (f) break;
                if (__builtin_amdgcn_s_memrealtime() - t0 > RT_1MS) { f = 0xffffffffu; break; }
                __builtin_amdgcn_s_sleep(1);
            }
            bool join = (f == 0xffffffffu) || (f - 1u == xcd);
            if (!join) {
                // cross-XCD: give the home XCD 200us to fill the team, then claim
                for (;;) {
                    if (__hip_atomic_load(&team[1], __ATOMIC_RELAXED, __HIP_MEMORY_SCOPE_AGENT) >= 15u)
                        break;
                    if (__builtin_amdgcn_s_memrealtime() - t0 > RT_200US) { join = true; break; }
                    __builtin_amdgcn_s_sleep(1);
                }
            }
            if (join) {
                unsigned s = __hip_atomic_fetch_add(&team[1], 1u, __ATOMIC_RELAXED, __HIP_MEMORY_SCOPE_AGENT);
                if (s < 15u) {
                    g = (int)s + 1;
                    __hip_atomic_store(&team[8 + g], xcd + 1u, __ATOMIC_RELEASE, __HIP_MEMORY_SCOPE_AGENT);
                }
            }
        }
        int homog = 0;
        if (g >= 0) {
            bool full;
            for (;;) {   // all 16 slots registered (guaranteed; bounded anyway)
                full = true;
                for (int i = 0; i < 16; i++)
                    if (__hip_atomic_load(&team[8 + i], __ATOMIC_ACQUIRE, __HIP_MEMORY_SCOPE_AGENT) == 0u)
                        { full = false; break; }
                if (full) break;
                if (__builtin_amdgcn_s_memrealtime() - t0 > RT_1MS) break;
                __builtin_amdgcn_s_sleep(1);
            }
            if (full) {  // census complete (all 256 WGs ran their entry code)
                while (__hip_atomic_load(&team[4], __ATOMIC_RELAXED, __HIP_MEMORY_SCOPE_AGENT) < (unsigned)GRID_LSTM) {
                    if (__builtin_amdgcn_s_memrealtime() - t0 > RT_1MS) { full = false; break; }
                    __builtin_amdgcn_s_sleep(1);
                }
            }
            if (full) {
                unsigned x0 = __hip_atomic_load(&team[8], __ATOMIC_RELAXED, __HIP_MEMORY_SCOPE_AGENT);
                homog = 1;
                for (int i = 1; i < 16; i++)
                    if (__hip_atomic_load(&team[8 + i], __ATOMIC_RELAXED, __HIP_MEMORY_SCOPE_AGENT) != x0)
                        homog = 0;
                unsigned msk = __hip_atomic_load(&team[3], __ATOMIC_RELAXED, __HIP_MEMORY_SCOPE_AGENT);
                if (__popc(msk) < 2) homog = 0;   // XCC_ID-read sanity guard
            }
        }
        s_g = g; s_homog = homog;
    }
    __syncthreads();
    const int g = s_g;
    bool fast = (s_homog != 0);
    if (g < 0) return;

    const int tid = threadIdx.x;
    const int wv = tid >> 6, lane = tid & 63, l15 = lane & 15, qd4 = lane >> 4;
    const float sih = ldexpf(1.0f, scale_exp(__uint_as_float(mx[1])) - 4);
    const float shh = ldexpf(1.0f, scale_exp(__uint_as_float(mx[2])) - 4);

    // Gate LUTs via XLA formulas (bit-exact policy from R6)
    if (tid < 256) {
        float v = (float)(tid - 128) * 0.125f;
        float sg = __fadd_rn(0.5f, __fmul_rn(0.5f, xla_tanhf(__fmul_rn(0.5f, v))));
        float sc = clampf(rintf(__fmul_rn(sg, 256.0f)), 0.0f, 255.0f);
        lut_sig[tid] = sc * 0.00390625f;
        float th = xla_tanhf(v);
        float tc = clampf(rintf(__fmul_rn(th, 128.0f)), -128.0f, 127.0f);
        lut_tnh[tid] = tc * 0.0078125f;
    }

    // Stage wih slice into LDS (used only by the prefetch GEMM)
    for (int it = 0; it < 16; it++) {
        int idx = it * 256 + tid;               // 16B chunks
        int r = idx >> 5, cc = (idx & 31) * 16;
        int grow = (r >> 5) * 512 + g * 32 + (r & 31);
        *(v4i*)(wih_lds + r * 528 + cc) = *(const v4i*)(wih8 + (size_t)grow * 512 + cc);
    }

    // whh slice fragments -> registers (64 x v4i; 1 wave/SIMD by design)
    v4i whf[8][8];
    #pragma unroll
    for (int nt = 0; nt < 8; nt++) {
        int nl = nt * 16 + l15;
        size_t grow = (size_t)((nl >> 5) * 512 + g * 32 + (nl & 31)) * 512;
        #pragma unroll
        for (int k = 0; k < 8; k++)
            whf[nt][k] = *(const v4i*)(whh8 + grow + k * 64 + qd4 * 16);
    }
    __syncthreads();   // LUTs + wih_lds ready (the ONLY workgroup barrier)

    // per-lane biases for the 8 N-tiles
    float bi[8], bh[8];
    #pragma unroll
    for (int nt = 0; nt < 8; nt++) {
        int nl = nt * 16 + l15;
        int col = (nl >> 5) * 512 + g * 32 + (nl & 31);
        bi[nt] = b_ih[col];
        bh[nt] = b_hh[col];
    }

    float cst[2][4];
    #pragma unroll
    for (int jh = 0; jh < 2; jh++)
        #pragma unroll
        for (int r = 0; r < 4; r++) cst[jh][r] = 0.0f;

    // input-gate accumulators for the CURRENT step (step 0 preloop)
    v4i xacc[8];
    {
        v4i xfr[8];
        const signed char* xrow = x8 + (size_t)(wv * 16 + l15) * 512 + qd4 * 16;
        #pragma unroll
        for (int k = 0; k < 8; k++) xfr[k] = *(const v4i*)(xrow + k * 64);
        #pragma unroll
        for (int nt = 0; nt < 8; nt++) {
            v4i a = (v4i){0, 0, 0, 0};
            #pragma unroll
            for (int k = 0; k < 8; k++) {
                v4i bf = *(const v4i*)(wih_lds + (nt * 16 + l15) * 528 + k * 64 + qd4 * 16);
                a = __builtin_amdgcn_mfma_i32_16x16x64_i8(xfr[k], bf, a, 0, 0, 0);
            }
            xacc[nt] = a;
        }
    }

    const int row = wv * 16 + l15;                       // this lane's batch row
    const int pb = tid >> 2, psub = tid & 3;             // producer unit: batch, sub
    const u64 paddr_base = (u64)(h8) + (u64)(pb * 64 + g * 4 + psub) * 16;
    const u64 caddr_base = (u64)(h8) + (u64)(row * 64 + qd4 * 2) * 16;
    // probe: one tag per producer WG pl (its wave-wv publish is ONE store
    // instruction covering rows wv*16..+15 x units pl*4..+3). Sample unit
    // (row wv*16+pl, unit pl*4); lanes 16-63 duplicate lanes 0-15 (merged).
    const int pl = lane & 15;
    const u64 probe_base = (u64)(h8) + (u64)((wv * 16 + pl) * 64 + pl * 4) * 16 + 8;

    for (int t = 0; t < S_LEN; t++) {
        u64 ha = caddr_base + (u64)(t & 1) * 65536;
        int tg = t;
        v4i u0,u1,u2,u3,u4,u5,u6,u7,u8,u9,u10,u11,u12,u13,u14,u15;

        // ---- fast discovery: 16-lane 1-dword tag probe at L2 latency ----
        if (fast) {
            u64 pra = probe_base + (u64)(t & 1) * 65536;
            int iters = 0;
            for (;;) {
                int tv;
                asm volatile("global_load_dword %0, %1, off sc0\n\t"
                             "s_waitcnt vmcnt(0)"
                             : "=&v"(tv) : "v"(pra) : "memory");
                if (__all(tv == tg)) break;
                if (++iters >= 768) { FALLBACK_SLOW; break; }   // ~100us stall
                __builtin_amdgcn_s_sleep(2);
            }
        }
        // ---- verified tagged round, L2 scope (fast) ----
        if (fast) {
            int iters = 0;
            for (;;) {
                H_POLL("sc0");
                if (H_TAGOK) break;
                if (++iters >= 512) { FALLBACK_SLOW; break; }
                __builtin_amdgcn_s_sleep(1);
            }
        }
        // ---- slow path: exact baseline poll (also entered after fallback) ----
        if (!fast) {
            for (;;) {
                H_POLL("sc0 sc1");
                if (H_TAGOK) break;
                __builtin_amdgcn_s_sleep(1);
            }
        }
        v4i afr[8];
        afr[0] = MKFRAG(u0, u1);   afr[1] = MKFRAG(u2, u3);
        afr[2] = MKFRAG(u4, u5);   afr[3] = MKFRAG(u6, u7);
        afr[4] = MKFRAG(u8, u9);   afr[5] = MKFRAG(u10, u11);
        afr[6] = MKFRAG(u12, u13); afr[7] = MKFRAG(u14, u15);

        // ---- hh GEMM (reg-resident B) + f32 pre-activations (ref association) ----
        float pre[8][4];
        #pragma unroll
        for (int nt = 0; nt < 8; nt++) {
            v4i hacc = (v4i){0, 0, 0, 0};
            #pragma unroll
            for (int k = 0; k < 8; k++)
                hacc = __builtin_amdgcn_mfma_i32_16x16x64_i8(afr[k], whf[nt][k], hacc, 0, 0, 0);
            #pragma unroll
            for (int r = 0; r < 4; r++)
                pre[nt][r] = __fadd_rn(
                    __fadd_rn(__fadd_rn(__fmul_rn((float)xacc[nt][r], sih), bi[nt]), bh[nt]),
                    __fmul_rn((float)hacc[r], shh));
        }

        // ---- gate math (bit-exact policy); stage h codes into wave-private LDS rows ----
        #pragma unroll
        for (int jh = 0; jh < 2; jh++)
            #pragma unroll
            for (int r = 0; r < 4; r++) {
                int ii = (int)clampf(rintf(__fmul_rn(pre[0 + jh][r], 8.0f)), -128.f, 127.f) + 128;
                int fi = (int)clampf(rintf(__fmul_rn(pre[2 + jh][r], 8.0f)), -128.f, 127.f) + 128;
                int gi = (int)clampf(rintf(__fmul_rn(pre[4 + jh][r], 8.0f)), -128.f, 127.f) + 128;
                int oi = (int)clampf(rintf(__fmul_rn(pre[6 + jh][r], 8.0f)), -128.f, 127.f) + 128;
                float iq = lut_sig[ii], fq = lut_sig[fi], oq = lut_sig[oi];
                float gq = lut_tnh[gi];
                float c = __fadd_rn(__fmul_rn(fq, cst[jh][r]), __fmul_rn(iq, gq));
                cst[jh][r] = c;
                float tc32 = xla_tanhf(c);
                float tq = clampf(rintf(__fmul_rn(tc32, 128.0f)), -128.f, 127.f) * 0.0078125f;
                float hv = __fmul_rn(oq, tq);
                int hc = (int)clampf(rintf(__fmul_rn(hv, 16.0f)), -128.f, 127.f);
                int b = wv * 16 + qd4 * 4 + r;
                hstage[b * 32 + jh * 16 + l15] = (signed char)hc;
            }

        // ---- publish h[t+1]: one tagged 16B store per thread ----
        // (hstage rows are wave-private: intra-wave LDS dep, no __syncthreads)
        {
            u64 codes = *(const u64*)(hstage + tid * 8);    // = hstage[pb*32 + psub*8]
            v4i sval = (v4i){(int)(codes & 0xffffffffu), (int)(codes >> 32), t + 1, 0};
            u64 pa = paddr_base + (u64)((t + 1) & 1) * 65536;
            if (fast)
                asm volatile("global_store_dwordx4 %0, %1, off sc0"
                             :: "v"(pa), "v"(sval) : "memory");
            else
                asm volatile("global_store_dwordx4 %0, %1, off sc0 sc1"
                             :: "v"(pa), "v"(sval) : "memory");
        }

        // ---- t+1 input-gate GEMM (hides the store flight + peers' publish) ----
        if (t + 1 < S_LEN) {
            v4i xfr[8];
            const signed char* xrow = x8 + (size_t)((t + 1) * BATCH + wv * 16 + l15) * 512 + qd4 * 16;
            #pragma unroll
            for (int k = 0; k < 8; k++) xfr[k] = *(const v4i*)(xrow + k * 64);
            #pragma unroll
            for (int nt = 0; nt < 8; nt++) {
                v4i a = (v4i){0, 0, 0, 0};
                #pragma unroll
                for (int k = 0; k < 8; k++) {
                    v4i bf = *(const v4i*)(wih_lds + (nt * 16 + l15) * 528 + k * 64 + qd4 * 16);
                    a = __builtin_amdgcn_mfma_i32_16x16x64_i8(xfr[k], bf, a, 0, 0, 0);
                }
                xacc[nt] = a;
            }
        }
    }
}

// ---------------- final FC: out[1,64,2] = h_T @ fc_q^T (exact int dot) ----------
// h[512] lives in slot 0 (tagged units); read codes via relaxed agent atomics.
// Fast-path h lines are dirty in one XCD's L2 at k_lstm end; the dispatch-end
// release flushes them (empirically validated in R2: fast mode + absmax 0.0).
__global__ void k_fc(const signed char* __restrict__ h8, const signed char* __restrict__ fc8,
                     const unsigned* __restrict__ mx_fc, float* __restrict__ out) {
    int tid = threadIdx.x;              // 128 threads = 64 b * 2 o
    int b = tid >> 1, o = tid & 1;
    const signed char* hp = h8 + b * 1024;          // 64 units * 16B per batch row
    const char4* wp = (const char4*)(fc8 + o * 512);
    int s = 0;
    for (int i = 0; i < 64; i++) {
        u64 hv = __hip_atomic_load((const u64*)(hp + i * 16), __ATOMIC_RELAXED, __HIP_MEMORY_SCOPE_AGENT);
        char4 w0 = wp[i * 2], w1 = wp[i * 2 + 1];
        signed char hb[8];
        *(u64*)hb = hv;
        s += hb[0] * w0.x + hb[1] * w0.y + hb[2] * w0.z + hb[3] * w0.w
           + hb[4] * w1.x + hb[5] * w1.y + hb[6] * w1.z + hb[7] * w1.w;
    }
    float sc = ldexpf(1.0f, scale_exp(__uint_as_float(*mx_fc)) - 4);
    out[b * 2 + o] = (float)s * sc;     // exact: s < 2^23, pow2 scale
}

extern "C" void kernel_launch(void* const* d_in, const int* in_sizes, int n_in,
                              void* d_out, int out_size, void* d_ws, size_t ws_size,
                              hipStream_t stream) {
    (void)in_sizes; (void)n_in; (void)out_size; (void)ws_size;
    const int*   text = (const int*)d_in[0];
    const float* emb  = (const float*)d_in[2];
    const float* w_ih = (const float*)d_in[3];
    const float* w_hh = (const float*)d_in[4];
    const float* b_ih = (const float*)d_in[5];
    const float* b_hh = (const float*)d_in[6];
    const float* fc_w = (const float*)d_in[7];

    char* ws = (char*)d_ws;
    unsigned*    team = (unsigned*)(ws + O_BAR);
    unsigned*    mx   = (unsigned*)(ws + O_MAX);
    signed char* h8   = (signed char*)(ws + O_H8);
    signed char* fc8  = (signed char*)(ws + O_FC8);
    signed char* wih8 = (signed char*)(ws + O_WIH8);
    signed char* whh8 = (signed char*)(ws + O_WHH8);
    signed char* x8   = (signed char*)(ws + O_X8);

    // zero team area + maxabs + BOTH tagged h slots (tags=0 == step-0 sentinel)
    hipMemsetAsync(d_ws, 0, O_H8 + 2 * 65536, stream);

    k_maxabs<<<2048, 256, 0, stream>>>(emb, VOCAB * E_DIM, mx + 0);
    k_maxabs<<<256, 256, 0, stream>>>(w_ih, G4 * E_DIM, mx + 1);
    k_maxabs<<<256, 256, 0, stream>>>(w_hh, G4 * H_DIM, mx + 2);
    k_maxabs<<<1, 256, 0, stream>>>(fc_w, 2 * H_DIM, mx + 3);

    k_quantw<<<512, 256, 0, stream>>>(w_ih, G4 * E_DIM, mx + 1, wih8);
    k_quantw<<<512, 256, 0, stream>>>(w_hh, G4 * H_DIM, mx + 2, whh8);
    k_quantw<<<2, 256, 0, stream>>>(fc_w, 2 * H_DIM, mx + 3, fc8);

    k_embed<<<BATCH * S_LEN, 128, 0, stream>>>(emb, text, mx + 0, x8);

    k_lstm<<<GRID_LSTM, 256, 0, stream>>>(wih8, whh8, x8, b_ih, b_hh, mx, h8, team);

    k_fc<<<1, 128, 0, stream>>>(h8, fc8, mx + 3, (float*)d_out);
}

// Round 7
// 3186.599 us; speedup vs baseline: 1.3632x; 1.3632x over previous
//
#include <hip/hip_runtime.h>
#include <math.h>

// Problem dims
#define S_LEN  512
#define BATCH  64
#define E_DIM  512
#define H_DIM  512
#define G4     2048          // 4*H
#define VOCAB  32000
#define NWG    16            // persistent LSTM workgroups (1 per 16 CUs; trivially co-resident)

typedef int v4i __attribute__((ext_vector_type(4)));
typedef unsigned long long u64;

// Workspace layout (bytes). Total ~19.0 MiB.  (Baseline layout, byte-identical.)
// h exchange: 2 slots x 64 batches x 64 units x 16B ({8 codes, 4B tag, 4B pad})
#define O_BAR   0                         // legacy/unused (memset-covered)
#define O_MAX   256                       // 4 uints: maxabs emb, ih, hh, fc
#define O_H8    512                       // 2 * 65536 B tagged h units
#define O_FC8   131584                    // 1024 int8
#define O_WIH8  132608                    // 2048*512 int8 (1 MiB)
#define O_WHH8  (O_WIH8 + 1048576)
#define O_X8    (O_WHH8 + 1048576)        // 512*64*512 int8 (16 MiB), t-major

__device__ __forceinline__ float clampf(float x, float lo, float hi) {
    return fminf(fmaxf(x, lo), hi);
}

// k = ceil(log2(maxabs/127)) via frexp (exact, no transcendental)
__device__ __forceinline__ int scale_exp(float maxabs) {
    double t = (double)maxabs / 127.0;
    int e; double f = frexp(t, &e);
    return (f == 0.5) ? (e - 1) : e;
}

// ---- XLA-CPU / Eigen fast tanh (f32), bit-exact vs the jax-CPU golden ------
__device__ __forceinline__ float xla_tanhf(float x) {
    if (fabsf(x) < 0.0004f) return x;
    float xc = fminf(fmaxf(x, -7.90531110763549805f), 7.90531110763549805f);
    float x2 = __fmul_rn(xc, xc);
    float p = fmaf(x2, -2.76076847742355e-16f, 2.00018790482477e-13f);
    p = fmaf(x2, p, -8.60467152213735e-11f);
    p = fmaf(x2, p, 5.12229709037114e-08f);
    p = fmaf(x2, p, 1.48572235717979e-05f);
    p = fmaf(x2, p, 6.37261928875436e-04f);
    p = fmaf(x2, p, 4.89352455891786e-03f);
    p = __fmul_rn(xc, p);
    float q = fmaf(x2, 1.19825839466702e-06f, 1.18534705686654e-04f);
    q = fmaf(x2, q, 2.26843463243900e-03f);
    q = fmaf(x2, q, 4.89352518554385e-03f);
    return __fdiv_rn(p, q);
}

// ---------------- maxabs reduction ----------------
__global__ void k_maxabs(const float* __restrict__ x, int n, unsigned* __restrict__ out) {
    unsigned m = 0;
    for (int i = blockIdx.x * blockDim.x + threadIdx.x; i < n; i += gridDim.x * blockDim.x)
        m = max(m, __float_as_uint(fabsf(x[i])));
    #pragma unroll
    for (int o = 32; o > 0; o >>= 1) {
        unsigned other = (unsigned)__shfl_down((int)m, o, 64);
        m = max(m, other);
    }
    __shared__ unsigned sm[4];
    if ((threadIdx.x & 63) == 0) sm[threadIdx.x >> 6] = m;
    __syncthreads();
    if (threadIdx.x == 0) {
        unsigned r = sm[0];
        for (int w = 1; w < (int)(blockDim.x >> 6); w++) r = max(r, sm[w]);
        atomicMax(out, r);
    }
}

// ---------------- weight quantization (exact: pow2 scale) ----------------
__global__ void k_quantw(const float* __restrict__ w, int n, const unsigned* __restrict__ mx,
                         signed char* __restrict__ q) {
    float inv = ldexpf(1.0f, -scale_exp(__uint_as_float(*mx)));
    for (int i = blockIdx.x * blockDim.x + threadIdx.x; i < n; i += gridDim.x * blockDim.x) {
        float v = clampf(rintf(w[i] * inv), -128.0f, 127.0f);
        q[i] = (signed char)(int)v;
    }
}

// ---------------- embedding lookup + double quantization (exact: pow2 scales) ----
__global__ void k_embed(const float* __restrict__ emb, const int* __restrict__ text,
                        const unsigned* __restrict__ mx, signed char* __restrict__ x8) {
    int row = blockIdx.x;                       // b*S + s (text is [B,S] row-major)
    int b = row >> 9, s = row & 511;
    int tok = text[row];
    int ke = scale_exp(__uint_as_float(*mx));
    float inv = ldexpf(1.0f, -ke);
    float sc2 = ldexpf(1.0f, ke + 4);
    const float4* src = (const float4*)(emb + (size_t)tok * E_DIM);
    char4* dst = (char4*)(x8 + (size_t)(s * BATCH + b) * E_DIM);
    float4 v = src[threadIdx.x];
    char4 c;
    float q;
    q = clampf(rintf(v.x * inv), -128.f, 127.f); c.x = (signed char)(int)clampf(rintf(q * sc2), -128.f, 127.f);
    q = clampf(rintf(v.y * inv), -128.f, 127.f); c.y = (signed char)(int)clampf(rintf(q * sc2), -128.f, 127.f);
    q = clampf(rintf(v.z * inv), -128.f, 127.f); c.z = (signed char)(int)clampf(rintf(q * sc2), -128.f, 127.f);
    q = clampf(rintf(v.w * inv), -128.f, 127.f); c.w = (signed char)(int)clampf(rintf(q * sc2), -128.f, 127.f);
    dst[threadIdx.x] = c;
}

#define MKFRAG(a, b) ((v4i){(a)[0], (a)[1], (b)[0], (b)[1]})

// ---------------- persistent fused LSTM, barrier-free tagged dataflow ----------
// Baseline protocol (proven 2737us): tagged 16B h units, 2-slot buffer,
// system-scope (sc0 sc1) stores/polls, row-partitioned reader/writer symmetry,
// no __syncthreads in the step loop. Numerics frozen.
//
// R7 delta (the ONLY change vs baseline, one instruction): s_waitcnt vmcnt(0)
// immediately after the publish store. Theory (fits ALL of R2-R6): the
// fire-and-forget publish lingers in the producer CU's write-combine buffer
// (lazy drain ~us) — that, not cache latency, is the ~10k-cycle step-period
// term. Evidence: R3 (data stores drained, flag not) was the only non-baseline
// variant to approach baseline; L2-local exchanges (R2/R6) were slow despite
// locality (WC sits before L2); atomics (WC-bypassing) are documented
// prompt-visible. The drain forces the tagged unit to the coherence point
// before the wave proceeds (~700cy, in place of a ~10k wait if the theory
// holds; +700cy/step bounded cost if it doesn't).
__global__ __launch_bounds__(256, 1) void k_lstm(
    const signed char* __restrict__ wih8, const signed char* __restrict__ whh8,
    const signed char* __restrict__ x8, const float* __restrict__ b_ih,
    const float* __restrict__ b_hh, const unsigned* __restrict__ mx,
    signed char* __restrict__ h8) {
    __shared__ __attribute__((aligned(16))) signed char wih_lds[128 * 528]; // rows padded 512->528
    __shared__ __attribute__((aligned(16))) signed char hstage[BATCH * 32]; // [b][jloc] codes
    __shared__ float lut_sig[256];
    __shared__ float lut_tnh[256];

    const int g = blockIdx.x;
    const int tid = threadIdx.x;
    const int wv = tid >> 6, lane = tid & 63, l15 = lane & 15, qd4 = lane >> 4;
    const float sih = ldexpf(1.0f, scale_exp(__uint_as_float(mx[1])) - 4);
    const float shh = ldexpf(1.0f, scale_exp(__uint_as_float(mx[2])) - 4);

    // Gate LUTs via XLA formulas (bit-exact policy from R6)
    if (tid < 256) {
        float v = (float)(tid - 128) * 0.125f;
        float sg = __fadd_rn(0.5f, __fmul_rn(0.5f, xla_tanhf(__fmul_rn(0.5f, v))));
        float sc = clampf(rintf(__fmul_rn(sg, 256.0f)), 0.0f, 255.0f);
        lut_sig[tid] = sc * 0.00390625f;
        float th = xla_tanhf(v);
        float tc = clampf(rintf(__fmul_rn(th, 128.0f)), -128.0f, 127.0f);
        lut_tnh[tid] = tc * 0.0078125f;
    }

    // Stage wih slice into LDS (used only by the prefetch GEMM)
    for (int it = 0; it < 16; it++) {
        int idx = it * 256 + tid;               // 16B chunks
        int r = idx >> 5, cc = (idx & 31) * 16;
        int grow = (r >> 5) * 512 + g * 32 + (r & 31);
        *(v4i*)(wih_lds + r * 528 + cc) = *(const v4i*)(wih8 + (size_t)grow * 512 + cc);
    }

    // whh slice fragments -> registers (64 x v4i; 1 wave/SIMD by design)
    v4i whf[8][8];
    #pragma unroll
    for (int nt = 0; nt < 8; nt++) {
        int nl = nt * 16 + l15;
        size_t grow = (size_t)((nl >> 5) * 512 + g * 32 + (nl & 31)) * 512;
        #pragma unroll
        for (int k = 0; k < 8; k++)
            whf[nt][k] = *(const v4i*)(whh8 + grow + k * 64 + qd4 * 16);
    }
    __syncthreads();   // LUTs + wih_lds ready (the ONLY workgroup barrier)

    // per-lane biases for the 8 N-tiles
    float bi[8], bh[8];
    #pragma unroll
    for (int nt = 0; nt < 8; nt++) {
        int nl = nt * 16 + l15;
        int col = (nl >> 5) * 512 + g * 32 + (nl & 31);
        bi[nt] = b_ih[col];
        bh[nt] = b_hh[col];
    }

    float cst[2][4];
    #pragma unroll
    for (int jh = 0; jh < 2; jh++)
        #pragma unroll
        for (int r = 0; r < 4; r++) cst[jh][r] = 0.0f;

    // input-gate accumulators for the CURRENT step (step 0 preloop)
    v4i xacc[8];
    {
        v4i xfr[8];
        const signed char* xrow = x8 + (size_t)(wv * 16 + l15) * 512 + qd4 * 16;
        #pragma unroll
        for (int k = 0; k < 8; k++) xfr[k] = *(const v4i*)(xrow + k * 64);
        #pragma unroll
        for (int nt = 0; nt < 8; nt++) {
            v4i a = (v4i){0, 0, 0, 0};
            #pragma unroll
            for (int k = 0; k < 8; k++) {
                v4i bf = *(const v4i*)(wih_lds + (nt * 16 + l15) * 528 + k * 64 + qd4 * 16);
                a = __builtin_amdgcn_mfma_i32_16x16x64_i8(xfr[k], bf, a, 0, 0, 0);
            }
            xacc[nt] = a;
        }
    }

    const int row = wv * 16 + l15;                       // this lane's batch row
    const int pb = tid >> 2, psub = tid & 3;             // producer unit: batch, sub
    const u64 paddr_base = (u64)(h8) + (u64)(pb * 64 + g * 4 + psub) * 16;
    const u64 caddr_base = (u64)(h8) + (u64)(row * 64 + qd4 * 2) * 16;

    for (int t = 0; t < S_LEN; t++) {
        // ---- poll + load h[t] fragments (slot t&1, tag t) ----
        u64 ha = caddr_base + (u64)(t & 1) * 65536;
        int tg = t;
        v4i u0,u1,u2,u3,u4,u5,u6,u7,u8,u9,u10,u11,u12,u13,u14,u15;
        for (;;) {
            asm volatile(
                "global_load_dwordx4 %0,  %16, off sc0 sc1\n\t"
                "global_load_dwordx4 %1,  %16, off offset:16 sc0 sc1\n\t"
                "global_load_dwordx4 %2,  %16, off offset:128 sc0 sc1\n\t"
                "global_load_dwordx4 %3,  %16, off offset:144 sc0 sc1\n\t"
                "global_load_dwordx4 %4,  %16, off offset:256 sc0 sc1\n\t"
                "global_load_dwordx4 %5,  %16, off offset:272 sc0 sc1\n\t"
                "global_load_dwordx4 %6,  %16, off offset:384 sc0 sc1\n\t"
                "global_load_dwordx4 %7,  %16, off offset:400 sc0 sc1\n\t"
                "global_load_dwordx4 %8,  %16, off offset:512 sc0 sc1\n\t"
                "global_load_dwordx4 %9,  %16, off offset:528 sc0 sc1\n\t"
                "global_load_dwordx4 %10, %16, off offset:640 sc0 sc1\n\t"
                "global_load_dwordx4 %11, %16, off offset:656 sc0 sc1\n\t"
                "global_load_dwordx4 %12, %16, off offset:768 sc0 sc1\n\t"
                "global_load_dwordx4 %13, %16, off offset:784 sc0 sc1\n\t"
                "global_load_dwordx4 %14, %16, off offset:896 sc0 sc1\n\t"
                "global_load_dwordx4 %15, %16, off offset:912 sc0 sc1\n\t"
                "s_waitcnt vmcnt(0)"
                : "=&v"(u0), "=&v"(u1), "=&v"(u2), "=&v"(u3),
                  "=&v"(u4), "=&v"(u5), "=&v"(u6), "=&v"(u7),
                  "=&v"(u8), "=&v"(u9), "=&v"(u10), "=&v"(u11),
                  "=&v"(u12), "=&v"(u13), "=&v"(u14), "=&v"(u15)
                : "v"(ha)
                : "memory");
            bool ok = (u0[2] == tg) & (u1[2] == tg) & (u2[2] == tg) & (u3[2] == tg)
                    & (u4[2] == tg) & (u5[2] == tg) & (u6[2] == tg) & (u7[2] == tg)
                    & (u8[2] == tg) & (u9[2] == tg) & (u10[2] == tg) & (u11[2] == tg)
                    & (u12[2] == tg) & (u13[2] == tg) & (u14[2] == tg) & (u15[2] == tg);
            if (ok) break;
            __builtin_amdgcn_s_sleep(1);
        }
        v4i afr[8];
        afr[0] = MKFRAG(u0, u1);   afr[1] = MKFRAG(u2, u3);
        afr[2] = MKFRAG(u4, u5);   afr[3] = MKFRAG(u6, u7);
        afr[4] = MKFRAG(u8, u9);   afr[5] = MKFRAG(u10, u11);
        afr[6] = MKFRAG(u12, u13); afr[7] = MKFRAG(u14, u15);

        // ---- hh GEMM (reg-resident B) + f32 pre-activations (ref association) ----
        float pre[8][4];
        #pragma unroll
        for (int nt = 0; nt < 8; nt++) {
            v4i hacc = (v4i){0, 0, 0, 0};
            #pragma unroll
            for (int k = 0; k < 8; k++)
                hacc = __builtin_amdgcn_mfma_i32_16x16x64_i8(afr[k], whf[nt][k], hacc, 0, 0, 0);
            #pragma unroll
            for (int r = 0; r < 4; r++)
                pre[nt][r] = __fadd_rn(
                    __fadd_rn(__fadd_rn(__fmul_rn((float)xacc[nt][r], sih), bi[nt]), bh[nt]),
                    __fmul_rn((float)hacc[r], shh));
        }

        // ---- gate math (bit-exact policy); stage h codes into wave-private LDS rows ----
        #pragma unroll
        for (int jh = 0; jh < 2; jh++)
            #pragma unroll
            for (int r = 0; r < 4; r++) {
                int ii = (int)clampf(rintf(__fmul_rn(pre[0 + jh][r], 8.0f)), -128.f, 127.f) + 128;
                int fi = (int)clampf(rintf(__fmul_rn(pre[2 + jh][r], 8.0f)), -128.f, 127.f) + 128;
                int gi = (int)clampf(rintf(__fmul_rn(pre[4 + jh][r], 8.0f)), -128.f, 127.f) + 128;
                int oi = (int)clampf(rintf(__fmul_rn(pre[6 + jh][r], 8.0f)), -128.f, 127.f) + 128;
                float iq = lut_sig[ii], fq = lut_sig[fi], oq = lut_sig[oi];
                float gq = lut_tnh[gi];
                float c = __fadd_rn(__fmul_rn(fq, cst[jh][r]), __fmul_rn(iq, gq));
                cst[jh][r] = c;
                float tc32 = xla_tanhf(c);
                float tq = clampf(rintf(__fmul_rn(tc32, 128.0f)), -128.f, 127.f) * 0.0078125f;
                float hv = __fmul_rn(oq, tq);
                int hc = (int)clampf(rintf(__fmul_rn(hv, 16.0f)), -128.f, 127.f);
                int b = wv * 16 + qd4 * 4 + r;
                hstage[b * 32 + jh * 16 + l15] = (signed char)hc;
            }

        // ---- publish h[t+1]: one tagged 16B store per thread + WC DRAIN ----
        // (hstage rows are wave-private: intra-wave LDS dep, no __syncthreads)
        {
            u64 codes = *(const u64*)(hstage + tid * 8);    // = hstage[pb*32 + psub*8]
            v4i sval = (v4i){(int)(codes & 0xffffffffu), (int)(codes >> 32), t + 1, 0};
            u64 pa = paddr_base + (u64)((t + 1) & 1) * 65536;
            asm volatile("global_store_dwordx4 %0, %1, off sc0 sc1\n\t"
                         "s_waitcnt vmcnt(0)"            // R7: force store to coherence point NOW
                         :: "v"(pa), "v"(sval) : "memory");
        }

        // ---- t+1 input-gate GEMM (hides peers' publish drain) ----
        if (t + 1 < S_LEN) {
            v4i xfr[8];
            const signed char* xrow = x8 + (size_t)((t + 1) * BATCH + wv * 16 + l15) * 512 + qd4 * 16;
            #pragma unroll
            for (int k = 0; k < 8; k++) xfr[k] = *(const v4i*)(xrow + k * 64);
            #pragma unroll
            for (int nt = 0; nt < 8; nt++) {
                v4i a = (v4i){0, 0, 0, 0};
                #pragma unroll
                for (int k = 0; k < 8; k++) {
                    v4i bf = *(const v4i*)(wih_lds + (nt * 16 + l15) * 528 + k * 64 + qd4 * 16);
                    a = __builtin_amdgcn_mfma_i32_16x16x64_i8(xfr[k], bf, a, 0, 0, 0);
                }
                xacc[nt] = a;
            }
        }
    }
}

// ---------------- final FC: out[1,64,2] = h_T @ fc_q^T (exact int dot) ----------
// h[512] lives in slot 0 (tagged units); read codes via relaxed agent atomics
// (bypass possibly-stale cached zero lines from the in-graph memset).
__global__ void k_fc(const signed char* __restrict__ h8, const signed char* __restrict__ fc8,
                     const unsigned* __restrict__ mx_fc, float* __restrict__ out) {
    int tid = threadIdx.x;              // 128 threads = 64 b * 2 o
    int b = tid >> 1, o = tid & 1;
    const signed char* hp = h8 + b * 1024;          // 64 units * 16B per batch row
    const char4* wp = (const char4*)(fc8 + o * 512);
    int s = 0;
    for (int i = 0; i < 64; i++) {
        u64 hv = __hip_atomic_load((const u64*)(hp + i * 16), __ATOMIC_RELAXED, __HIP_MEMORY_SCOPE_AGENT);
        char4 w0 = wp[i * 2], w1 = wp[i * 2 + 1];
        signed char hb[8];
        *(u64*)hb = hv;
        s += hb[0] * w0.x + hb[1] * w0.y + hb[2] * w0.z + hb[3] * w0.w
           + hb[4] * w1.x + hb[5] * w1.y + hb[6] * w1.z + hb[7] * w1.w;
    }
    float sc = ldexpf(1.0f, scale_exp(__uint_as_float(*mx_fc)) - 4);
    out[b * 2 + o] = (float)s * sc;     // exact: s < 2^23, pow2 scale
}

extern "C" void kernel_launch(void* const* d_in, const int* in_sizes, int n_in,
                              void* d_out, int out_size, void* d_ws, size_t ws_size,
                              hipStream_t stream) {
    (void)in_sizes; (void)n_in; (void)out_size; (void)ws_size;
    const int*   text = (const int*)d_in[0];
    const float* emb  = (const float*)d_in[2];
    const float* w_ih = (const float*)d_in[3];
    const float* w_hh = (const float*)d_in[4];
    const float* b_ih = (const float*)d_in[5];
    const float* b_hh = (const float*)d_in[6];
    const float* fc_w = (const float*)d_in[7];

    char* ws = (char*)d_ws;
    unsigned*    mx   = (unsigned*)(ws + O_MAX);
    signed char* h8   = (signed char*)(ws + O_H8);
    signed char* fc8  = (signed char*)(ws + O_FC8);
    signed char* wih8 = (signed char*)(ws + O_WIH8);
    signed char* whh8 = (signed char*)(ws + O_WHH8);
    signed char* x8   = (signed char*)(ws + O_X8);

    // zero maxabs + BOTH tagged h slots (tags=0 == step-0 sentinel; h0=0 codes)
    hipMemsetAsync(d_ws, 0, O_H8 + 2 * 65536, stream);

    k_maxabs<<<2048, 256, 0, stream>>>(emb, VOCAB * E_DIM, mx + 0);
    k_maxabs<<<256, 256, 0, stream>>>(w_ih, G4 * E_DIM, mx + 1);
    k_maxabs<<<256, 256, 0, stream>>>(w_hh, G4 * H_DIM, mx + 2);
    k_maxabs<<<1, 256, 0, stream>>>(fc_w, 2 * H_DIM, mx + 3);

    k_quantw<<<512, 256, 0, stream>>>(w_ih, G4 * E_DIM, mx + 1, wih8);
    k_quantw<<<512, 256, 0, stream>>>(w_hh, G4 * H_DIM, mx + 2, whh8);
    k_quantw<<<2, 256, 0, stream>>>(fc_w, 2 * H_DIM, mx + 3, fc8);

    k_embed<<<BATCH * S_LEN, 128, 0, stream>>>(emb, text, mx + 0, x8);

    k_lstm<<<NWG, 256, 0, stream>>>(wih8, whh8, x8, b_ih, b_hh, mx, h8);

    k_fc<<<1, 128, 0, stream>>>(h8, fc8, mx + 3, (float*)d_out);
}